// Round 2
// baseline (242.464 us; speedup 1.0000x reference)
//
#include <hip/hip_runtime.h>

#define MODE_QKV 0
#define MODE_S   1
#define MODE_PV  2

typedef __attribute__((ext_vector_type(8))) short short8;
typedef __attribute__((ext_vector_type(4))) float floatx4;

typedef const unsigned __attribute__((address_space(1)))* gp_t;
typedef unsigned __attribute__((address_space(3)))* lp_t;

__device__ __forceinline__ void async16(const void* g, void* l) {
  // stages 16B/lane: LDS dest = wave-uniform base + lane*16
  __builtin_amdgcn_global_load_lds((gp_t)g, (lp_t)l, 16, 0, 0);
}

__device__ __forceinline__ unsigned short f2bf(float f) {
  union { float f; unsigned u; } x; x.f = f;
  unsigned r = x.u + 0x7fffu + ((x.u >> 16) & 1u);
  return (unsigned short)(r >> 16);
}
__device__ __forceinline__ float bf2f(unsigned short h) {
  union { unsigned u; float f; } x; x.u = ((unsigned)h) << 16;
  return x.f;
}

// ===========================================================================
// R5: 256x256 8-phase kernel (T2 swizzle + T3/T4 counted vmcnt + T5 setprio)
// for MODE_QKV and MODE_S. PV stays on the legacy 128^2 kernel (its 256^2
// grid would be 128 blocks = half the machine at 1 block/CU).
//
// Geometry: BM=BN=256, BK=64, 512 thr = 8 waves (2M x 4N). Per-wave output
// 128x64 arranged as rows {wm*64..+64} u {128+wm*64..}, cols {wn*32..+32} u
// {128+wn*32..}. LDS = 2 buf x 4 halves (A0,A1,B0,B1) x 16 KB = 128 KB.
// Each half = 128 rows x 64 k bf16, XOR-swizzled: physical chunk =
// logical_chunk ^ (row&7) (16B chunks). global_load_lds writes linearly, so
// the swizzle is applied by permuting the per-lane GLOBAL source address
// (inverse == forward, XOR involution); ds_read applies the same XOR.
// 64 lanes of a b128 frag read then touch each bank exactly twice -> no
// conflicts.
//
// Phase schedule per K-tile j (buf c = j&1), quadrant = (mh,nh):
//   p0: read A(mh=0) 8x + B(nh=0) 4x b128 | issue Ah1(j+1)->buf c^1 | bar;
//       lgkm0; prio1; 16 MFMA q00; prio0; bar
//   p1: read B(nh=1) 4x                   | issue Ah0(j+2)->buf c   | ...q01
//   p2: read A(mh=1) 8x                   | issue Bh0(j+2)->buf c   | ...q10
//   p3: issue Bh1(j+2)->buf c; vmcnt(6)   | bar; 16 MFMA q11; bar
// Exactly 3 half-tiles (6 loads) in flight at each p3 wait; every half
// lands >=1 full tile before its first read (checked per-half).
// ===========================================================================

__device__ __forceinline__ void stage_half(const unsigned short* gp, long rowbase,
                                           int ldk, int kb, char* region,
                                           int wave, int lane) {
  const int rs = lane >> 3;                    // row within 8-row group
  const int kc = ((lane & 7) ^ rs) << 3;       // pre-swizzled k-chunk (elems)
  #pragma unroll
  for (int h = 0; h < 2; h++) {
    const int rr = (h * 8 + wave) * 8 + rs;    // row within 128-row half
    async16(gp + (rowbase + rr) * (long)ldk + kb + kc,
            region + (h * 8 + wave) * 1024);
  }
}

__device__ __forceinline__ short8 frag(const char* region, int hr, int ks, int quad) {
  // logical chunk = ks*4+quad; physical = chunk ^ (hr&7); 16B chunks, 128B rows
  return *(const short8*)(region + hr * 128 + ((((ks << 2) | quad) ^ (hr & 7)) << 4));
}

#define MFMA_QUAD(MH, NH)                                                    \
  do {                                                                       \
    _Pragma("unroll")                                                        \
    for (int mi_ = 0; mi_ < 4; mi_++) {                                      \
      _Pragma("unroll")                                                      \
      for (int jj_ = 0; jj_ < 2; jj_++) {                                    \
        _Pragma("unroll")                                                    \
        for (int ks_ = 0; ks_ < 2; ks_++) {                                  \
          acc[MH][mi_][NH][jj_] = __builtin_amdgcn_mfma_f32_16x16x32_bf16(   \
              a[mi_][ks_], b[NH][jj_][ks_], acc[MH][mi_][NH][jj_], 0, 0, 0); \
        }                                                                    \
      }                                                                      \
    }                                                                        \
  } while (0)

template<int MODE>
__global__ __launch_bounds__(512, 1)
void gemm256(const unsigned short* __restrict__ A,
             const unsigned short* __restrict__ Bmat,
             const float* __restrict__ b0, const float* __restrict__ b1,
             const float* __restrict__ b2,
             unsigned short* __restrict__ O0, unsigned short* __restrict__ O1,
             unsigned short* __restrict__ O2, float* __restrict__ lsum,
             int M, int N, int K, long aZ, long bZ, long cZ, float scale)
{
  __shared__ __attribute__((aligned(128))) char lds[131072];

  const int tid = threadIdx.x;
  const int wave = tid >> 6, lane = tid & 63;
  const int wm = wave >> 2, wn = wave & 3;
  const int quad = lane >> 4, l16 = lane & 15;

  // ---- XCD-aware 4x4-square swizzle (requires total blocks % 128 == 0) ----
  const int gx = gridDim.x, gy = gridDim.y;
  int z, bm, bn;
  {
    int f = (blockIdx.z * gy + blockIdx.y) * gx + blockIdx.x;
    int T = gx * gy * (int)gridDim.z;
    int nsq = T >> 7;
    int xcd = f & 7, i = f >> 3;
    int sq = xcd * nsq + (i >> 4);
    int w = i & 15;
    int spz = (gx >> 2) * (gy >> 2);
    z = sq / spz;
    int sqr = sq - z * spz;
    int sqm = sqr / (gx >> 2), sqn = sqr - sqm * (gx >> 2);
    bm = (sqm * 4 + (w >> 2)) * 256;
    bn = (sqn * 4 + (w & 3)) * 256;
  }

  const unsigned short* Ap = (MODE == MODE_QKV) ? A : (A + (long)z * aZ);
  const unsigned short* Bp = Bmat + (long)z * bZ;

  const int NT = K >> 6;

  // region offsets within a buffer: A0=0, A1=16384, B0=32768, B1=49152
  // prologue: A0(0) B0(0) B1(0) A1(0) A0(1) B0(1) B1(1) -> vmcnt(6) leaves
  // exactly the 3 tile-1 halves outstanding, all of tile 0 landed.
  stage_half(Ap, bm,       K, 0,  lds +     0, wave, lane);
  stage_half(Bp, bn,       K, 0,  lds + 32768, wave, lane);
  stage_half(Bp, bn + 128, K, 0,  lds + 49152, wave, lane);
  stage_half(Ap, bm + 128, K, 0,  lds + 16384, wave, lane);
  stage_half(Ap, bm,       K, 64, lds + 65536 +     0, wave, lane);
  stage_half(Bp, bn,       K, 64, lds + 65536 + 32768, wave, lane);
  stage_half(Bp, bn + 128, K, 64, lds + 65536 + 49152, wave, lane);
  asm volatile("s_waitcnt vmcnt(6)" ::: "memory");
  __builtin_amdgcn_s_barrier();

  floatx4 acc[2][4][2][2];   // [mh][mi][nh][jj]
  #pragma unroll
  for (int p = 0; p < 2; p++)
    #pragma unroll
    for (int q2 = 0; q2 < 4; q2++)
      #pragma unroll
      for (int r = 0; r < 2; r++)
        #pragma unroll
        for (int s = 0; s < 2; s++)
          acc[p][q2][r][s] = (floatx4){0.f, 0.f, 0.f, 0.f};

  short8 a[4][2];      // current mh's A frags [mi][ks]
  short8 b[2][2][2];   // both nh's B frags    [nh][jj][ks]

  for (int j = 0; j < NT; j++) {
    char* bufc = lds + ((j & 1) << 16);
    char* bufn = lds + (((j + 1) & 1) << 16);
    const bool lp = (j + 2 >= NT);
    const int kn  = (j + 1) << 6;
    const int kn2 = (j + 2) << 6;

    // ---- phase 0 : q(0,0) ----
    #pragma unroll
    for (int mi = 0; mi < 4; mi++)
      #pragma unroll
      for (int ks = 0; ks < 2; ks++)
        a[mi][ks] = frag(bufc, wm * 64 + mi * 16 + l16, ks, quad);
    #pragma unroll
    for (int jj = 0; jj < 2; jj++)
      #pragma unroll
      for (int ks = 0; ks < 2; ks++)
        b[0][jj][ks] = frag(bufc + 32768, wn * 32 + jj * 16 + l16, ks, quad);
    if (j + 1 < NT)
      stage_half(Ap, bm + 128, K, kn, bufn + 16384, wave, lane);   // Ah1(j+1)
    __builtin_amdgcn_s_barrier();
    asm volatile("s_waitcnt lgkmcnt(0)" ::: "memory");
    __builtin_amdgcn_sched_barrier(0);
    __builtin_amdgcn_s_setprio(1);
    MFMA_QUAD(0, 0);
    __builtin_amdgcn_s_setprio(0);
    __builtin_amdgcn_s_barrier();

    // ---- phase 1 : q(0,1) ----
    #pragma unroll
    for (int jj = 0; jj < 2; jj++)
      #pragma unroll
      for (int ks = 0; ks < 2; ks++)
        b[1][jj][ks] = frag(bufc + 49152, wn * 32 + jj * 16 + l16, ks, quad);
    if (!lp)
      stage_half(Ap, bm, K, kn2, bufc, wave, lane);                // Ah0(j+2)
    __builtin_amdgcn_s_barrier();
    asm volatile("s_waitcnt lgkmcnt(0)" ::: "memory");
    __builtin_amdgcn_sched_barrier(0);
    __builtin_amdgcn_s_setprio(1);
    MFMA_QUAD(0, 1);
    __builtin_amdgcn_s_setprio(0);
    __builtin_amdgcn_s_barrier();

    // ---- phase 2 : q(1,0) ----
    #pragma unroll
    for (int mi = 0; mi < 4; mi++)
      #pragma unroll
      for (int ks = 0; ks < 2; ks++)
        a[mi][ks] = frag(bufc + 16384, wm * 64 + mi * 16 + l16, ks, quad);
    if (!lp)
      stage_half(Bp, bn, K, kn2, bufc + 32768, wave, lane);        // Bh0(j+2)
    __builtin_amdgcn_s_barrier();
    asm volatile("s_waitcnt lgkmcnt(0)" ::: "memory");
    __builtin_amdgcn_sched_barrier(0);
    __builtin_amdgcn_s_setprio(1);
    MFMA_QUAD(1, 0);
    __builtin_amdgcn_s_setprio(0);
    __builtin_amdgcn_s_barrier();

    // ---- phase 3 : q(1,1) ----
    if (!lp) {
      stage_half(Bp, bn + 128, K, kn2, bufc + 49152, wave, lane);  // Bh1(j+2)
      asm volatile("s_waitcnt vmcnt(6)" ::: "memory");
    } else {
      asm volatile("s_waitcnt vmcnt(0)" ::: "memory");
    }
    __builtin_amdgcn_s_barrier();
    __builtin_amdgcn_s_setprio(1);
    MFMA_QUAD(1, 1);
    __builtin_amdgcn_s_setprio(0);
    __builtin_amdgcn_s_barrier();
  }
  // all staging drained (vmcnt(0) at tile NT-2, no issues after); last
  // barrier passed -> LDS reusable as epilogue buffer.

  const bool vtrans = (MODE == MODE_QKV) && (z == 2);
  float bi[2][2];
  if (MODE == MODE_QKV) {
    const float* bias = (z == 0) ? b0 : ((z == 1) ? b1 : b2);
    #pragma unroll
    for (int nh = 0; nh < 2; nh++)
      #pragma unroll
      for (int jj = 0; jj < 2; jj++)
        bi[nh][jj] = bias[bn + nh * 128 + wn * 32 + jj * 16 + l16];
  }

  unsigned short* epi = (unsigned short*)lds;
  // two passes of 128 rows (pass = mh). normal/S: epi[128][264]; vtrans
  // (v output [B][D][S]): epi[256][136] transposed.
  #pragma unroll
  for (int mh = 0; mh < 2; mh++) {
    #pragma unroll
    for (int mi = 0; mi < 4; mi++) {
      const int r0 = wm * 64 + mi * 16 + quad * 4;
      #pragma unroll
      for (int nh = 0; nh < 2; nh++)
        #pragma unroll
        for (int jj = 0; jj < 2; jj++) {
          const int col = nh * 128 + wn * 32 + jj * 16 + l16;
          if (MODE == MODE_S) {
            #pragma unroll
            for (int r = 0; r < 4; r++)
              epi[(r0 + r) * 264 + col] = f2bf(__expf(acc[mh][mi][nh][jj][r] * scale));
          } else if (!vtrans) {
            #pragma unroll
            for (int r = 0; r < 4; r++)
              epi[(r0 + r) * 264 + col] = f2bf(acc[mh][mi][nh][jj][r] + bi[nh][jj]);
          } else {
            #pragma unroll
            for (int r = 0; r < 4; r += 2) {
              unsigned lo = f2bf(acc[mh][mi][nh][jj][r] + bi[nh][jj]);
              unsigned hi = f2bf(acc[mh][mi][nh][jj][r + 1] + bi[nh][jj]);
              *(unsigned*)&epi[col * 136 + r0 + r] = lo | (hi << 16);
            }
          }
        }
    }
    __syncthreads();

    if (!vtrans) {
      #pragma unroll
      for (int it = 0; it < 8; it++) {
        int flat = it * 4096 + tid * 8;
        int rr = flat >> 8, cc = flat & 255;
        short8 vline = *(const short8*)&epi[rr * 264 + cc];
        long grow = bm + mh * 128 + rr;
        if (MODE == MODE_S) {
          union { short8 v; unsigned short u[8]; } t; t.v = vline;
          float s8 = 0.f;
          #pragma unroll
          for (int jq = 0; jq < 8; jq++) s8 += bf2f(t.u[jq]);
          s8 += __shfl_xor(s8, 1);
          s8 += __shfl_xor(s8, 2);
          s8 += __shfl_xor(s8, 4);
          s8 += __shfl_xor(s8, 8);
          s8 += __shfl_xor(s8, 16);
          if ((lane & 31) == 0) atomicAdd(&lsum[(long)z * M + grow], s8);
          *(short8*)&O0[(long)z * cZ + grow * N + bn + cc] = vline;
        } else {
          unsigned short* O = (z == 0) ? O0 : O1;
          *(short8*)&O[grow * N + bn + cc] = vline;
        }
      }
    } else {
      int bb = bm >> 11, s0 = bm & 2047;  // S=2048; 256-row tiles don't straddle batch
      #pragma unroll
      for (int it = 0; it < 8; it++) {
        int flat = it * 4096 + tid * 8;
        int dd = flat >> 7, ss = flat & 127;
        short8 vline = *(const short8*)&epi[dd * 136 + ss];
        *(short8*)&O2[(long)bb * (1024L * 2048) + (long)(bn + dd) * 2048 + s0 + mh * 128 + ss] = vline;
      }
    }
    if (mh == 0) __syncthreads();
  }
}

// ===========================================================================
// Legacy 128x128 kernel (kept for MODE_PV full path + fallback S/PV path)
// ===========================================================================

union SmemU {
  struct { unsigned short A[2][4096]; unsigned short B[2][4096]; } st;  // 32 KB
  unsigned short epi[128 * 136];                                        // 34816 B
};

template<int MODE>
__global__ __launch_bounds__(256, 4)
void gemm_nt(const unsigned short* __restrict__ A,
             const unsigned short* __restrict__ Bmat,
             const float* __restrict__ b0, const float* __restrict__ b1,
             const float* __restrict__ b2,
             unsigned short* __restrict__ O0, unsigned short* __restrict__ O1,
             unsigned short* __restrict__ O2,
             float* __restrict__ Of, float* __restrict__ lsum,
             int M, int N, int K, long aZ, long bZ, long cZ, float scale)
{
  __shared__ SmemU smem;

  const int tid = threadIdx.x;
  const int wave = tid >> 6, lane = tid & 63;
  const int wm = wave >> 1, wn = wave & 1;
  const int quad = lane >> 4, l16 = lane & 15;

  const int gx = gridDim.x, gy = gridDim.y;
  int z, bm, bn;
  {
    int f = (blockIdx.z * gy + blockIdx.y) * gx + blockIdx.x;
    int T = gx * gy * (int)gridDim.z;
    int nsq = T >> 7;
    int xcd = f & 7, i = f >> 3;
    int sq = xcd * nsq + (i >> 4);
    int w = i & 15;
    int spz = (gx >> 2) * (gy >> 2);
    z = sq / spz;
    int sqr = sq - z * spz;
    int sqm = sqr / (gx >> 2), sqn = sqr - sqm * (gx >> 2);
    bm = (sqm * 4 + (w >> 2)) * 128;
    bn = (sqn * 4 + (w & 3)) * 128;
  }

  const unsigned short* Ap = (MODE == MODE_QKV) ? A : (A + (long)z * aZ);
  const unsigned short* Bp = Bmat + (long)z * bZ;

  floatx4 acc[4][4];
  #pragma unroll
  for (int i = 0; i < 4; i++)
    #pragma unroll
    for (int j = 0; j < 4; j++)
      acc[i][j] = (floatx4){0.f, 0.f, 0.f, 0.f};

  char* asb = (char*)&smem.st.A[0][0] + wave * 1024;
  char* bsb = (char*)&smem.st.B[0][0] + wave * 1024;

  for (int k0 = 0; k0 < K; k0 += 64) {
    #pragma unroll
    for (int p = 0; p < 2; p++) {
      #pragma unroll
      for (int h = 0; h < 2; h++) {
        int flat = tid + h * 256;
        int r = flat >> 2, c = (flat & 3) << 3;
        async16(Ap + (long)(bm + r) * K + k0 + p * 32 + c,
                asb + p * 8192 + h * 4096);
        async16(Bp + (long)(bn + r) * K + k0 + p * 32 + c,
                bsb + p * 8192 + h * 4096);
      }
    }
    __syncthreads();

    #pragma unroll
    for (int ks = 0; ks < 2; ks++) {
      short8 afr[4], bfr[4];
      #pragma unroll
      for (int i = 0; i < 4; i++)
        afr[i] = *(const short8*)&smem.st.A[ks][(wm * 64 + i * 16 + l16) * 32 + quad * 8];
      #pragma unroll
      for (int i = 0; i < 4; i++)
        bfr[i] = *(const short8*)&smem.st.B[ks][(wn * 64 + i * 16 + l16) * 32 + quad * 8];
      #pragma unroll
      for (int mi = 0; mi < 4; mi++)
        #pragma unroll
        for (int ni = 0; ni < 4; ni++)
          acc[mi][ni] = __builtin_amdgcn_mfma_f32_16x16x32_bf16(
              afr[mi], bfr[ni], acc[mi][ni], 0, 0, 0);
    }
    __syncthreads();
  }

  if (MODE == MODE_PV) {
    #pragma unroll
    for (int mi = 0; mi < 4; mi++) {
      int row0 = bm + wm * 64 + mi * 16 + quad * 4;
      float inv[4];
      #pragma unroll
      for (int r = 0; r < 4; r++)
        inv[r] = 1.0f / lsum[(long)z * M + row0 + r];
      #pragma unroll
      for (int ni = 0; ni < 4; ni++) {
        int col = bn + wn * 64 + ni * 16 + l16;
        #pragma unroll
        for (int r = 0; r < 4; r++)
          Of[(long)z * cZ + (long)(row0 + r) * N + col] = acc[mi][ni][r] * inv[r];
      }
    }
    return;
  }

  const bool vtrans = (MODE == MODE_QKV) && (z == 2);
  float bi[4];
  if (MODE == MODE_QKV) {
    const float* bias = (z == 0) ? b0 : ((z == 1) ? b1 : b2);
    #pragma unroll
    for (int ni = 0; ni < 4; ni++) bi[ni] = bias[bn + wn * 64 + ni * 16 + l16];
  }

  #pragma unroll
  for (int ni = 0; ni < 4; ni++) {
    int col = wn * 64 + ni * 16 + l16;
    float bb = (MODE == MODE_QKV) ? bi[ni] : 0.f;
    #pragma unroll
    for (int mi = 0; mi < 4; mi++) {
      int row0 = wm * 64 + mi * 16 + quad * 4;
      if (MODE == MODE_S) {
        #pragma unroll
        for (int r = 0; r < 4; r++)
          smem.epi[(row0 + r) * 136 + col] = f2bf(__expf(acc[mi][ni][r] * scale));
      } else if (!vtrans) {
        #pragma unroll
        for (int r = 0; r < 4; r++)
          smem.epi[(row0 + r) * 136 + col] = f2bf(acc[mi][ni][r] + bb);
      } else {
        #pragma unroll
        for (int r = 0; r < 4; r += 2) {
          unsigned lo = f2bf(acc[mi][ni][r] + bb);
          unsigned hi = f2bf(acc[mi][ni][r + 1] + bb);
          *(unsigned*)&smem.epi[col * 136 + row0 + r] = lo | (hi << 16);
        }
      }
    }
  }
  __syncthreads();

  #pragma unroll
  for (int i = 0; i < 8; i++) {
    int flat = i * 2048 + tid * 8;
    int rr = flat >> 7, cc = flat & 127;
    short8 vline = *(const short8*)&smem.epi[rr * 136 + cc];
    if (MODE == MODE_S) {
      union { short8 v; unsigned short u[8]; } t; t.v = vline;
      float s8 = 0.f;
      #pragma unroll
      for (int j = 0; j < 8; j++) s8 += bf2f(t.u[j]);
      s8 += __shfl_xor(s8, 1);
      s8 += __shfl_xor(s8, 2);
      s8 += __shfl_xor(s8, 4);
      s8 += __shfl_xor(s8, 8);
      if ((lane & 15) == 0) atomicAdd(&lsum[(long)z * M + bm + rr], s8);
      *(short8*)&O0[(long)z * cZ + (long)(bm + rr) * N + bn + cc] = vline;
    } else if (!vtrans) {
      unsigned short* O = (z == 0) ? O0 : O1;
      *(short8*)&O[(long)(bm + rr) * N + bn + cc] = vline;
    } else {
      int bb = bm >> 11, s0 = bm & 2047;
      *(short8*)&O2[(long)bb * (1024L * 2048) + (long)(bn + rr) * 2048 + s0 + cc] = vline;
    }
  }
}

// Fused prep: [0,4096) x fp32->bf16; [4096,7168) W transpose->bf16;
// [7168,7200) zero the 8192-float lsum buffer.
__global__ __launch_bounds__(256)
void prep_kernel(const float* __restrict__ x, unsigned short* __restrict__ xb,
                 const float* __restrict__ W0, const float* __restrict__ W1,
                 const float* __restrict__ W2, unsigned short* __restrict__ Wt,
                 float* __restrict__ lsum) {
  int blk = blockIdx.x;
  if (blk < 4096) {
    long i = ((long)blk * 256 + threadIdx.x) * 8;
    float4 a = *(const float4*)(x + i);
    float4 b = *(const float4*)(x + i + 4);
    union { int4 v; unsigned short u[8]; } t;
    t.u[0] = f2bf(a.x); t.u[1] = f2bf(a.y); t.u[2] = f2bf(a.z); t.u[3] = f2bf(a.w);
    t.u[4] = f2bf(b.x); t.u[5] = f2bf(b.y); t.u[6] = f2bf(b.z); t.u[7] = f2bf(b.w);
    *(int4*)(xb + i) = t.v;
  } else if (blk < 7168) {
    __shared__ float tile[32][33];
    int tt = blk - 4096;
    int zz = tt >> 10, rem = tt & 1023;
    int kb = (rem >> 5) * 32, nb = (rem & 31) * 32;
    const float* W = (zz == 0) ? W0 : ((zz == 1) ? W1 : W2);
    unsigned short* O = Wt + (long)zz * 1024 * 1024;
    int t = threadIdx.x, tr = t >> 5, tc = t & 31;
    #pragma unroll
    for (int i = 0; i < 4; i++)
      tile[tr + i * 8][tc] = W[(long)(kb + tr + i * 8) * 1024 + nb + tc];
    __syncthreads();
    #pragma unroll
    for (int i = 0; i < 4; i++)
      O[(long)(nb + tr + i * 8) * 1024 + kb + tc] = f2bf(tile[tc][tr + i * 8]);
  } else {
    int i = (blk - 7168) * 256 + threadIdx.x;  // 32*256 = 8192 floats
    lsum[i] = 0.f;
  }
}

extern "C" void kernel_launch(void* const* d_in, const int* in_sizes, int n_in,
                              void* d_out, int out_size, void* d_ws, size_t ws_size,
                              hipStream_t stream) {
  const float* x  = (const float*)d_in[0];
  const float* Wq = (const float*)d_in[1];
  const float* bq = (const float*)d_in[2];
  const float* Wk = (const float*)d_in[3];
  const float* bk = (const float*)d_in[4];
  const float* Wv = (const float*)d_in[5];
  const float* bv = (const float*)d_in[6];
  float* out = (float*)d_out;

  const int B = 4, S = 2048, D = 1024;
  const int M = B * S;
  const float scale = 0.03125f;  // 1/sqrt(1024)

  // xb (16 MiB) + Wt (6 MiB) borrow d_out's first 22 MiB; dead before the
  // PV GEMM overwrites all of d_out.
  unsigned short* xb = (unsigned short*)d_out;
  unsigned short* Wt = xb + (size_t)M * D;
  unsigned short* q  = (unsigned short*)d_ws;
  unsigned short* k  = q + (size_t)M * D;
  unsigned short* vT = k + (size_t)M * D;
  unsigned short* P  = vT + (size_t)M * D;

  size_t need_full = ((size_t)3 * M * D + (size_t)B * S * S) * sizeof(unsigned short)
                   + (size_t)M * sizeof(float);
  const bool full = (ws_size >= need_full);
  float* lsum = full ? (float*)(P + (size_t)B * S * S)
                     : (float*)(P + (size_t)S * S);

  prep_kernel<<<7200, 256, 0, stream>>>(x, xb, Wq, Wk, Wv, Wt, lsum);

  gemm256<MODE_QKV><<<dim3(D / 256, M / 256, 3), 512, 0, stream>>>(
      xb, Wt, bq, bk, bv, q, k, vT, nullptr,
      M, D, D, 0, (long)D * D, 0, 1.0f);

  if (full) {
    gemm256<MODE_S><<<dim3(S / 256, S / 256, B), 512, 0, stream>>>(
        q, k, nullptr, nullptr, nullptr, P, nullptr, nullptr, lsum,
        S, S, D, (long)S * D, (long)S * D, (long)S * S, scale);
    gemm_nt<MODE_PV><<<dim3(D / 128, S / 128, B), 256, 0, stream>>>(
        P, vT, nullptr, nullptr, nullptr, nullptr, nullptr, nullptr, out, lsum,
        S, D, S, (long)S * S, (long)D * S, (long)S * D, 1.0f);
  } else {
    for (int b = 0; b < B; b++) {
      const unsigned short* qb = q + (size_t)b * S * D;
      const unsigned short* kb = k + (size_t)b * S * D;
      const unsigned short* vb = vT + (size_t)b * S * D;
      float* ob = out + (size_t)b * S * D;
      gemm_nt<MODE_S><<<dim3(S / 128, S / 128, 1), 256, 0, stream>>>(
          qb, kb, nullptr, nullptr, nullptr, P, nullptr, nullptr, nullptr,
          lsum + (size_t)b * S,
          S, S, D, 0, 0, 0, scale);
      gemm_nt<MODE_PV><<<dim3(D / 128, S / 128, 1), 256, 0, stream>>>(
          P, vb, nullptr, nullptr, nullptr, nullptr, nullptr, nullptr, ob,
          lsum + (size_t)b * S,
          S, D, S, 0, 0, 0, 1.0f);
    }
  }
}